// Round 6
// baseline (321.542 us; speedup 1.0000x reference)
//
#include <hip/hip_runtime.h>

#define BLOCK 256
#define NB 5      // objects per scene
#define DD 12     // per-object feature dim
#define EE 64     // goal embedding dim
#define HH 32     // F1 hidden dim
#define ROW 81    // D + E + N
#define OUTW 405  // N * ROW
#define TILE 64   // rows per block in assemble kernel
#define TPB 4     // threads per batch item in zhat kernel
#define HPT (HH / TPB)   // 8 hidden units per thread

// ---------------- kernel A: compute zhat[B,5], 4 threads per batch ----------------
__global__ __launch_bounds__(BLOCK) void zhat_kernel(
    const float* __restrict__ obs, const float* __restrict__ ghat,
    const float* __restrict__ W1, const float* __restrict__ b1,
    const float* __restrict__ W2, const float* __restrict__ b2,
    float* __restrict__ zbuf, int zstride, int zoff, int B)
{
    __shared__ float s_W1t[HH * 2 * DD];   // W1 transposed: [h][d], 24 floats/row
    __shared__ float s_w2s[HH];            // rowsum(W2)
    __shared__ float s_sb2;                // sum(b2)

    const int tid = threadIdx.x;

    // stage W1^T + per-h W2 rowsums (threads 0..31 each own one h)
    if (tid < HH) {
        float s = 0.f;
        const float4* p = reinterpret_cast<const float4*>(W2 + tid * EE);
        #pragma unroll
        for (int q = 0; q < EE / 4; ++q) { float4 v = p[q]; s += (v.x + v.y) + (v.z + v.w); }
        s_w2s[tid] = s;
        #pragma unroll
        for (int d = 0; d < 2 * DD; ++d) s_W1t[tid * (2 * DD) + d] = W1[d * HH + tid];
    } else if (tid == HH) {
        float s = 0.f;
        #pragma unroll
        for (int e = 0; e < EE; ++e) s += b2[e];
        s_sb2 = s;
    }
    __syncthreads();

    const int g  = tid & (TPB - 1);        // quad lane: which h-subset
    const int il = tid >> 2;               // batch slot within block (0..63)
    const int i  = blockIdx.x * (BLOCK / TPB) + il;
    if (i >= B) return;                    // quad-coherent; no barriers below

    // ---- GEMV: g2[hp] = W2[h,:] . ghat_i  for h = g + 4*hp (L1-hot float4) ----
    float g2[HPT];
    #pragma unroll
    for (int hp = 0; hp < HPT; ++hp) g2[hp] = 0.f;
    const float* grow = ghat + (size_t)i * EE;
    #pragma unroll 4
    for (int ec = 0; ec < EE / 4; ++ec) {
        const float4 gv = reinterpret_cast<const float4*>(grow)[ec];
        #pragma unroll
        for (int hp = 0; hp < HPT; ++hp) {
            const float4 wv = reinterpret_cast<const float4*>(W2 + (g + TPB * hp) * EE)[ec];
            g2[hp] += gv.x * wv.x + gv.y * wv.y + gv.z * wv.z + gv.w * wv.w;
        }
    }

    // ---- obs row into registers (quad-redundant; same lines, L1) ----
    float o[NB * DD];
    {
        const float4* p = reinterpret_cast<const float4*>(obs + (size_t)i * (NB * DD));
        #pragma unroll
        for (int q = 0; q < NB * DD / 4; ++q) {
            float4 v = p[q];
            o[4*q+0] = v.x; o[4*q+1] = v.y; o[4*q+2] = v.z; o[4*q+3] = v.w;
        }
    }

    // ---- pass 1: logits over this thread's 8 hidden units ----
    float w[NB * NB];
    #pragma unroll
    for (int q = 0; q < NB * NB; ++q) w[q] = 0.f;

    #pragma unroll
    for (int hp = 0; hp < HPT; ++hp) {
        const int h = g + TPB * hp;
        float a[NB], bb[NB];
        const float b1h = b1[h];
        #pragma unroll
        for (int j = 0; j < NB; ++j) { a[j] = b1h; bb[j] = 0.f; }
        const float* w1r = &s_W1t[h * (2 * DD)];
        #pragma unroll
        for (int dc = 0; dc < 3; ++dc) {               // top half: a[j]
            const float4 wv = reinterpret_cast<const float4*>(w1r)[dc];
            const float wl[4] = {wv.x, wv.y, wv.z, wv.w};
            #pragma unroll
            for (int d4 = 0; d4 < 4; ++d4) {
                const int d = dc * 4 + d4;
                #pragma unroll
                for (int j = 0; j < NB; ++j) a[j] += o[j*DD + d] * wl[d4];
            }
        }
        #pragma unroll
        for (int dc = 0; dc < 3; ++dc) {               // bottom half: bb[k]
            const float4 wv = reinterpret_cast<const float4*>(w1r + DD)[dc];
            const float wl[4] = {wv.x, wv.y, wv.z, wv.w};
            #pragma unroll
            for (int d4 = 0; d4 < 4; ++d4) {
                const int d = dc * 4 + d4;
                #pragma unroll
                for (int j = 0; j < NB; ++j) bb[j] += o[j*DD + d] * wl[d4];
            }
        }
        const float gv = g2[hp];
        #pragma unroll
        for (int j = 0; j < NB; ++j)
            #pragma unroll
            for (int k = 0; k < NB; ++k)
                w[j*NB + k] += fmaxf(a[j] + bb[k], 0.f) * gv;
    }

    // ---- quad reduction of logits (DPP xor within quad) ----
    #pragma unroll
    for (int q = 0; q < NB * NB; ++q) {
        w[q] += __shfl_xor(w[q], 1);
        w[q] += __shfl_xor(w[q], 2);
    }

    // ---- softmax (redundant in all 4 lanes; identical results) ----
    float m = w[0];
    #pragma unroll
    for (int q = 1; q < NB * NB; ++q) m = fmaxf(m, w[q]);
    #pragma unroll
    for (int q = 0; q < NB * NB; ++q) w[q] = __expf(w[q] - m);   // w := unnorm p
    float l = 0.f;
    float racc[NB];
    #pragma unroll
    for (int j = 0; j < NB; ++j) {
        float r = 0.f;
        #pragma unroll
        for (int k = 0; k < NB; ++k) r += w[j*NB + k];
        racc[j] = r; l += r;
    }

    // ---- pass 2: recompute hv, accumulate zacc[j] = sum_h w2s[h] * sum_k p*hv ----
    float zacc[NB];
    #pragma unroll
    for (int j = 0; j < NB; ++j) zacc[j] = 0.f;

    #pragma unroll
    for (int hp = 0; hp < HPT; ++hp) {
        const int h = g + TPB * hp;
        float a[NB], bb[NB];
        const float b1h = b1[h];
        #pragma unroll
        for (int j = 0; j < NB; ++j) { a[j] = b1h; bb[j] = 0.f; }
        const float* w1r = &s_W1t[h * (2 * DD)];
        #pragma unroll
        for (int dc = 0; dc < 3; ++dc) {
            const float4 wv = reinterpret_cast<const float4*>(w1r)[dc];
            const float wl[4] = {wv.x, wv.y, wv.z, wv.w};
            #pragma unroll
            for (int d4 = 0; d4 < 4; ++d4) {
                const int d = dc * 4 + d4;
                #pragma unroll
                for (int j = 0; j < NB; ++j) a[j] += o[j*DD + d] * wl[d4];
            }
        }
        #pragma unroll
        for (int dc = 0; dc < 3; ++dc) {
            const float4 wv = reinterpret_cast<const float4*>(w1r + DD)[dc];
            const float wl[4] = {wv.x, wv.y, wv.z, wv.w};
            #pragma unroll
            for (int d4 = 0; d4 < 4; ++d4) {
                const int d = dc * 4 + d4;
                #pragma unroll
                for (int j = 0; j < NB; ++j) bb[j] += o[j*DD + d] * wl[d4];
            }
        }
        const float ws = s_w2s[h];
        #pragma unroll
        for (int j = 0; j < NB; ++j) {
            float racc2 = 0.f;
            #pragma unroll
            for (int k = 0; k < NB; ++k)
                racc2 += w[j*NB + k] * fmaxf(a[j] + bb[k], 0.f);
            zacc[j] += ws * racc2;
        }
    }

    // ---- quad reduction of zacc; lane g==0 writes ----
    #pragma unroll
    for (int j = 0; j < NB; ++j) {
        zacc[j] += __shfl_xor(zacc[j], 1);
        zacc[j] += __shfl_xor(zacc[j], 2);
    }
    if (g == 0) {
        const float invl = 1.f / l;
        const float sb2 = s_sb2;
        float* zr = zbuf + (size_t)i * zstride + zoff;
        #pragma unroll
        for (int j = 0; j < NB; ++j)
            zr[j] = (zacc[j] + sb2 * racc[j]) * invl;
    }
}

// ---------------- kernel B: assemble output (proven R3 path) ----------------
__global__ __launch_bounds__(BLOCK) void assemble_kernel(
    const float* __restrict__ obs, const float* __restrict__ ghat,
    const float* __restrict__ zbuf, int zstride, int zoff,
    float* __restrict__ out, int B)
{
    __shared__ float s_obs[TILE * NB * DD];  // 3840 floats
    __shared__ float s_gh[TILE * EE];        // 4096 floats
    __shared__ float s_zh[TILE * NB];        // 320 floats

    const int tid = threadIdx.x;
    const int r0 = blockIdx.x * TILE;
    const int rows = (B - r0 < TILE) ? (B - r0) : TILE;

    for (int t = tid; t < rows * NB * DD; t += BLOCK)
        s_obs[t] = obs[(size_t)r0 * NB * DD + t];
    for (int t = tid; t < rows * EE; t += BLOCK)
        s_gh[t] = ghat[(size_t)r0 * EE + t];
    for (int t = tid; t < rows * NB; t += BLOCK) {
        const int row = t / NB, k = t - row * NB;
        s_zh[t] = zbuf[(size_t)(r0 + row) * zstride + zoff + k];
    }
    __syncthreads();

    const size_t base = (size_t)r0 * OUTW;
    for (int t = tid; t < rows * OUTW; t += BLOCK) {
        const int il = t / OUTW;
        const int r  = t - il * OUTW;
        const int j  = r / ROW;
        const int rr = r - j * ROW;
        float v;
        if (rr < DD)           v = s_obs[il * NB * DD + j * DD + rr];
        else if (rr < DD + EE) v = s_gh[il * EE + (rr - DD)];
        else                   v = s_zh[il * NB + (rr - (DD + EE))];
        out[base + t] = v;
    }
}

extern "C" void kernel_launch(void* const* d_in, const int* in_sizes, int n_in,
                              void* d_out, int out_size, void* d_ws, size_t ws_size,
                              hipStream_t stream) {
    const float* obs  = (const float*)d_in[0];
    const float* ghat = (const float*)d_in[1];
    const float* W1   = (const float*)d_in[2];
    const float* b1   = (const float*)d_in[3];
    const float* W2   = (const float*)d_in[4];
    const float* b2   = (const float*)d_in[5];
    float* out = (float*)d_out;

    const int B = in_sizes[0] / (NB * DD);

    // zhat scratch: d_ws if large enough, else stash in last 5 floats of each
    // output row (assemble reads its tile's stash before overwriting it).
    float* zbuf; int zstride, zoff;
    if (ws_size >= (size_t)B * NB * sizeof(float)) {
        zbuf = (float*)d_ws; zstride = NB;   zoff = 0;
    } else {
        zbuf = out;          zstride = OUTW; zoff = OUTW - NB;
    }

    const int gridA = (B + (BLOCK / TPB) - 1) / (BLOCK / TPB);
    hipLaunchKernelGGL(zhat_kernel, dim3(gridA), dim3(BLOCK), 0, stream,
                       obs, ghat, W1, b1, W2, b2, zbuf, zstride, zoff, B);

    const int gridB = (B + TILE - 1) / TILE;
    hipLaunchKernelGGL(assemble_kernel, dim3(gridB), dim3(BLOCK), 0, stream,
                       obs, ghat, zbuf, zstride, zoff, out, B);
}